// Round 1
// baseline (890.067 us; speedup 1.0000x reference)
//
#include <hip/hip_runtime.h>

#define T_STEPS 32
#define BATCH   16
#define NBPB    8                    // blocks per batch
#define NBLK    (BATCH * NBPB)       // 128
#define NTHR    1024
#define LSL     512                  // l-slots per block
#define MSTR    68                   // 16B-aligned rows; with 4-float XOR swizzle -> <=2-way banks
#define NIN     192
#define CO      332

// comm workspace (floats), zeroed by hipMemsetAsync each launch
#define OFF_CTR   0                                        // [16][32] uints (barrier ctrs)
#define OFF_SSUM  512                                      // [b][t][4]  S_R,S_W,P_R,P_W
#define OFF_RSUM  (OFF_SSUM + BATCH * T_STEPS * 4)         // [b][t][64] unnormalized read partials
#define OFF_HE    (OFF_RSUM + BATCH * T_STEPS * 64)        // [b][t][g][4] er halos
#define OFF_HP    (OFF_HE + BATCH * T_STEPS * NBPB * 4)    // [b][t=0..32][g][4] normalized wp halos
#define COMM_FLOATS (OFF_HP + BATCH * (T_STEPS + 1) * NBPB * 4)

__device__ __forceinline__ float waveSum(float v) {
#pragma unroll
  for (int off = 32; off > 0; off >>= 1) v += __shfl_xor(v, off, 64);
  return v;
}
__device__ __forceinline__ float sigmoidf(float x) { return 1.f / (1.f + __expf(-x)); }
__device__ __forceinline__ float softplusf(float x) { return x > 15.f ? x : log1pf(__expf(x)); }
__device__ __forceinline__ float aload(const float* p) {
  return __hip_atomic_load(p, __ATOMIC_RELAXED, __HIP_MEMORY_SCOPE_AGENT);
}
__device__ __forceinline__ void astore(float* p, float v) {
  __hip_atomic_store(p, v, __ATOMIC_RELAXED, __HIP_MEMORY_SCOPE_AGENT);
}
// all-thread spin; producer bumps with RELEASE so prior atomics are drained first
__device__ __forceinline__ void spin_until(const unsigned* c, unsigned expected) {
  while (__hip_atomic_load(c, __ATOMIC_RELAXED, __HIP_MEMORY_SCOPE_AGENT) < expected)
    __builtin_amdgcn_s_sleep(1);
}

__global__ void __launch_bounds__(NTHR, 1) ntm_kernel(
    const float* __restrict__ inp, const float* __restrict__ Wc,
    const float* __restrict__ bcv, float* __restrict__ dout,
    float* __restrict__ comm)
{
  // XCD co-location: blockIdx = g*16 + b -> all 8 blocks of a batch on one XCD.
  const int b    = blockIdx.x & 15;
  const int g    = blockIdx.x >> 4;
  const int tid  = threadIdx.x;
  const int wv   = tid >> 6;
  const int lane = tid & 63;

  __shared__ __align__(16) float mem[LSL * MSTR];          // 139 KB, block-private
  __shared__ float wpR[LSL], wpW[LSL];                     // normalized prev weights
  __shared__ float wbR[LSL], wbW[LSL];                     // sharpened, unnormalized
  __shared__ float erR[LSL], erW[LSL];                     // softmax numerators
  __shared__ __align__(16) float xin[NIN];
  __shared__ __align__(16) float kr[64], kw[64], elds[64], alds[64];
  __shared__ float psc[12], outb[64], scrA[16], scrB[16];

  unsigned* ctr = (unsigned*)comm + b * 32;

  // GEMM role: 2 threads per output column
  const int col  = tid >> 1;
  const int hh   = tid & 1;
  const bool gthr = (col < CO);

  // r-part Wc rows 128..191 in registers (loop-invariant): 32 VGPRs/thread
  float wreg[32];
  if (gthr) {
#pragma unroll
    for (int i = 0; i < 32; ++i)
      wreg[i] = Wc[(size_t)(128 + 32 * hh + i) * CO + col];
  }

  // ---------------- prologue ----------------
  {
    float4 z4; z4.x = z4.y = z4.z = z4.w = 0.f;
    float4* m4 = (float4*)mem;
    for (int i = tid; i < (LSL * MSTR) / 4; i += NTHR) m4[i] = z4;
  }
  if (tid < LSL) { wpR[tid] = 0.f; wpW[tid] = 0.f; }
  if (g == 0 && tid == 0) { wpR[0] = 1.f; wpW[0] = 1.f; }   // w0 one-hot at l=0
  if (tid < 64)            xin[tid] = inp[(size_t)b * 64 + tid];   // x_0
  else if (tid < NIN)      xin[tid] = 0.f;                          // out_{-1}=0, r_{-1}=0
  {
    float* hp0 = comm + OFF_HP + ((size_t)(b * (T_STEPS + 1)) * NBPB + g) * 4;
    if (tid == 0) { float v = (g == 0) ? 1.f : 0.f; astore(hp0 + 0, v); astore(hp0 + 2, v); }
    if (tid == 1) { astore(hp0 + 1, 0.f); astore(hp0 + 3, 0.f); }
  }
  unsigned expct = NBPB;
  __syncthreads();
  if (tid == 0)
    __hip_atomic_fetch_add(ctr, 1u, __ATOMIC_RELEASE, __HIP_MEMORY_SCOPE_AGENT);
  spin_until(ctr, expct);

  // initial GEMM: co_0 (r-part is zeros, included for uniformity)
  float acc = 0.f;
  if (gthr) {
    acc = hh ? 0.f : bcv[col];
    const float* wcx = Wc + col + (size_t)(64 * hh) * CO;
#pragma unroll 4
    for (int q = 0; q < 16; ++q) {
      const float4 xv = *(const float4*)(xin + 64 * hh + 4 * q);
      acc = fmaf(xv.x, wcx[(size_t)(4 * q + 0) * CO], acc);
      acc = fmaf(xv.y, wcx[(size_t)(4 * q + 1) * CO], acc);
      acc = fmaf(xv.z, wcx[(size_t)(4 * q + 2) * CO], acc);
      acc = fmaf(xv.w, wcx[(size_t)(4 * q + 3) * CO], acc);
    }
#pragma unroll
    for (int q = 0; q < 8; ++q) {
      const float4 xv = *(const float4*)(xin + 128 + 32 * hh + 4 * q);
      acc = fmaf(xv.x, wreg[4 * q + 0], acc);
      acc = fmaf(xv.y, wreg[4 * q + 1], acc);
      acc = fmaf(xv.z, wreg[4 * q + 2], acc);
      acc = fmaf(xv.w, wreg[4 * q + 3], acc);
    }
  }

  const int gm = (g + NBPB - 1) & 7, gp = (g + 1) & 7;

  for (int t = 0; t < T_STEPS; ++t) {
    float* sS        = comm + OFF_SSUM + (size_t)(b * T_STEPS + t) * 4;
    float* rS        = comm + OFF_RSUM + (size_t)(b * T_STEPS + t) * 64;
    float* hE        = comm + OFF_HE + ((size_t)(b * T_STEPS + t) * NBPB + g) * 4;
    float* hPn       = comm + OFF_HP + ((size_t)(b * (T_STEPS + 1) + t + 1) * NBPB + g) * 4;
    const float* hEm = comm + OFF_HE + ((size_t)(b * T_STEPS + t) * NBPB + gm) * 4;
    const float* hPm = comm + OFF_HP + ((size_t)(b * (T_STEPS + 1) + t) * NBPB + gm) * 4;
    const float* hEp = comm + OFF_HE + ((size_t)(b * T_STEPS + t) * NBPB + gp) * 4;
    const float* hPp = comm + OFF_HP + ((size_t)(b * (T_STEPS + 1) + t) * NBPB + gp) * 4;

    // ------- finalize co_t outputs from register accumulators -------
    if (gthr) {
      float v = acc + __shfl_xor(acc, 1, 64);
      if (hh == 0) {
        if (col < 64) {
          outb[col] = v;
          if (g == 0) dout[((size_t)t * BATCH + b) * 64 + col] = v;
        }
        else if (col < 128) kr[col - 64] = v;
        else if (col < 134) psc[col - 128] = v;        // beta_r,g_r,ga_r,s_r0..2
        else if (col < 198) kw[col - 134] = v;
        else if (col < 204) psc[6 + (col - 198)] = v;  // beta_w,g_w,ga_w,s_w0..2
        else if (col < 268) elds[col - 204] = sigmoidf(v);
        else                alds[col - 268] = v;
      }
    }
    __syncthreads();                                    // S1: co_t outputs visible

    // ------- P1: content addressing (2 threads per l, b128 reads) -------
    {
      // per-wave redundant key norms (no cross-wave sync needed)
      float vr = kr[lane]; float nr = waveSum(vr * vr);
      float vw = kw[lane]; float nw = waveSum(vw * vw);
      const float invnkR = rsqrtf(nr + 1e-14f);
      const float invnkW = rsqrtf(nw + 1e-14f);
      const float betaR = softplusf(psc[0]), betaW = softplusf(psc[6]);

      const int l = tid >> 1, h = tid & 1;
      const int x4 = ((l >> 3) & 3) << 2;
      const float* mrow = mem + l * MSTR;
      float ss = 0.f, dr = 0.f, dw = 0.f;
#pragma unroll
      for (int q = 0; q < 8; ++q) {
        const int gg = 8 * h + q;
        const float4 v  = *(const float4*)(mrow + ((4 * gg) ^ x4));
        const float4 ka = *(const float4*)(kr + 4 * gg);
        const float4 kb = *(const float4*)(kw + 4 * gg);
        ss = fmaf(v.x, v.x, ss); ss = fmaf(v.y, v.y, ss);
        ss = fmaf(v.z, v.z, ss); ss = fmaf(v.w, v.w, ss);
        dr = fmaf(v.x, ka.x, dr); dr = fmaf(v.y, ka.y, dr);
        dr = fmaf(v.z, ka.z, dr); dr = fmaf(v.w, ka.w, dr);
        dw = fmaf(v.x, kb.x, dw); dw = fmaf(v.y, kb.y, dw);
        dw = fmaf(v.z, kb.z, dw); dw = fmaf(v.w, kb.w, dw);
      }
      ss += __shfl_xor(ss, 1, 64);
      dr += __shfl_xor(dr, 1, 64);
      dw += __shfl_xor(dw, 1, 64);
      float rinv = rsqrtf(ss + 1e-14f);
      float eRv = __expf(betaR * (dr * rinv * invnkR - 1.f));   // stable: K<=1
      float eWv = __expf(betaW * (dw * rinv * invnkW - 1.f));
      if (h == 0) {
        erR[l] = eRv; erW[l] = eWv;
        if (l == 0)       { astore(hE + 0, eRv); astore(hE + 2, eWv); }
        if (l == LSL - 1) { astore(hE + 1, eRv); astore(hE + 3, eWv); }
      }
      float sRl = waveSum(h ? 0.f : eRv);
      float sWl = waveSum(h ? 0.f : eWv);
      if (!lane) { scrA[wv] = sRl; scrB[wv] = sWl; }
    }
    // ------- barrier A (publish folded into barrier; all threads spin) -------
    __syncthreads();                                    // S2: drains halos+scr
    if (tid == 0) {
      float a = 0.f, bb = 0.f;
#pragma unroll
      for (int j = 0; j < 16; ++j) { a += scrA[j]; bb += scrB[j]; }
      atomicAdd(sS + 0, a); atomicAdd(sS + 1, bb);
      __hip_atomic_fetch_add(ctr, 1u, __ATOMIC_RELEASE, __HIP_MEMORY_SCOPE_AGENT);
    }
    expct += NBPB;
    spin_until(ctr, expct);

    // ------- P2: sharpen (head-split: h=0 read head, h=1 write head) -------
    {
      const int l = tid >> 1, h = tid & 1;
      const float S = aload(sS + h);                    // L2 broadcast, all threads
      const float gg_ = sigmoidf(psc[6 * h + 1]);
      const float aH = gg_ / S, bH = 1.f - gg_;
      const float gaH = softplusf(psc[6 * h + 2]) + 1.f;
      float x0 = psc[6 * h + 3], x1 = psc[6 * h + 4], x2 = psc[6 * h + 5];
      float mx = fmaxf(x0, fmaxf(x1, x2));
      float e0 = __expf(x0 - mx), e1 = __expf(x1 - mx), e2 = __expf(x2 - mx);
      float es = 1.f / (e0 + e1 + e2);
      const float c0 = e0 * es, c1 = e1 * es, c2 = e2 * es;

      const float* er = h ? erW : erR;
      const float* wp = h ? wpW : wpR;
      float em, pm, ep, pp;
      if (l == 0) { em = aload(hEm + 2 * h + 1); pm = aload(hPm + 2 * h + 1); }
      else        { em = er[l - 1];              pm = wp[l - 1]; }
      if (l == LSL - 1) { ep = aload(hEp + 2 * h); pp = aload(hPp + 2 * h); }
      else              { ep = er[l + 1];          pp = wp[l + 1]; }

      float wgm = aH * em + bH * pm;
      float wg0 = aH * er[l] + bH * wp[l];
      float wgp = aH * ep + bH * pp;
      float wb = __powf(c0 * wgm + c1 * wg0 + c2 * wgp, gaH);
      (h ? wbW : wbR)[l] = wb;
      float sRl = waveSum(h ? 0.f : wb);
      float sWl = waveSum(h ? wb : 0.f);
      if (!lane) { scrA[wv] = sRl; scrB[wv] = sWl; }
    }
    // stage next-step xin[0..127] (x_{t+1}, out_t) before the barrier sync
    {
      const int tt = (t + 1 < T_STEPS) ? (t + 1) : (T_STEPS - 1);
      if (tid < 64)       xin[tid] = inp[((size_t)tt * BATCH + b) * 64 + tid];
      else if (tid < 128) xin[tid] = outb[tid - 64];
    }
    __syncthreads();                                    // S3: wb + xin visible

    // ------- unnormalized read partials over OLD memory (b128 rows) -------
    {
      float4 racc; racc.x = racc.y = racc.z = racc.w = 0.f;
#pragma unroll
      for (int k = 0; k < 8; ++k) {
        const int l2 = lane + 64 * k;
        const float wbl = wbR[l2];
        const float4 v = *(const float4*)(mem + l2 * MSTR +
                           ((4 * wv) ^ (((l2 >> 3) & 3) << 2)));
        racc.x = fmaf(v.x, wbl, racc.x);
        racc.y = fmaf(v.y, wbl, racc.y);
        racc.z = fmaf(v.z, wbl, racc.z);
        racc.w = fmaf(v.w, wbl, racc.w);
      }
      racc.x = waveSum(racc.x); racc.y = waveSum(racc.y);
      racc.z = waveSum(racc.z); racc.w = waveSum(racc.w);
      if (!lane) {
        atomicAdd(rS + 4 * wv + 0, racc.x);
        atomicAdd(rS + 4 * wv + 1, racc.y);
        atomicAdd(rS + 4 * wv + 2, racc.z);
        atomicAdd(rS + 4 * wv + 3, racc.w);
      }
    }
    // ------- barrier B + xo-GEMM of co_{t+1} overlapped into the wait -------
    __syncthreads();                                    // S4: drains rS atomics + scr
    if (tid == 0) {
      float a = 0.f, bb = 0.f;
#pragma unroll
      for (int j = 0; j < 16; ++j) { a += scrA[j]; bb += scrB[j]; }
      atomicAdd(sS + 2, a); atomicAdd(sS + 3, bb);
      __hip_atomic_fetch_add(ctr, 1u, __ATOMIC_RELEASE, __HIP_MEMORY_SCOPE_AGENT);
    }
    expct += NBPB;
    float nacc = 0.f;
    if (gthr) {                                         // x/out part of co_{t+1}
      nacc = hh ? 0.f : bcv[col];
      const float* wcx = Wc + col + (size_t)(64 * hh) * CO;
#pragma unroll 4
      for (int q = 0; q < 16; ++q) {
        const float4 xv = *(const float4*)(xin + 64 * hh + 4 * q);
        nacc = fmaf(xv.x, wcx[(size_t)(4 * q + 0) * CO], nacc);
        nacc = fmaf(xv.y, wcx[(size_t)(4 * q + 1) * CO], nacc);
        nacc = fmaf(xv.z, wcx[(size_t)(4 * q + 2) * CO], nacc);
        nacc = fmaf(xv.w, wcx[(size_t)(4 * q + 3) * CO], nacc);
      }
    }
    spin_until(ctr, expct);

    // ------- P3: normalize weights + memory update (no extra syncs) -------
    const float invPR = 1.f / aload(sS + 2);            // L2 broadcast
    const float invPW = 1.f / aload(sS + 3);
    {
      const int l = tid >> 1, h = tid & 1;
      {
        const float nv = (h ? wbW : wbR)[l] * (h ? invPW : invPR);
        (h ? wpW : wpR)[l] = nv;                        // w_prev for t+1
        if (l == 0)       astore(hPn + 2 * h + 0, nv);
        if (l == LSL - 1) astore(hPn + 2 * h + 1, nv);
      }
      const float wl = wbW[l] * invPW;
      const int x4 = ((l >> 3) & 3) << 2;
      float* mrow = mem + l * MSTR;
#pragma unroll
      for (int q = 0; q < 8; ++q) {
        const int gg = 8 * h + q;
        float* p = mrow + ((4 * gg) ^ x4);
        float4 v = *(float4*)p;
        const float4 e4 = *(const float4*)(elds + 4 * gg);
        const float4 a4 = *(const float4*)(alds + 4 * gg);
        v.x = fmaf(wl, a4.x, fmaf(-(wl * e4.x), v.x, v.x));
        v.y = fmaf(wl, a4.y, fmaf(-(wl * e4.y), v.y, v.y));
        v.z = fmaf(wl, a4.z, fmaf(-(wl * e4.z), v.z, v.z));
        v.w = fmaf(wl, a4.w, fmaf(-(wl * e4.w), v.w, v.w));
        *(float4*)p = v;
      }
    }
    // stage normalized read vector for co_{t+1}
    if (tid < 64) xin[128 + tid] = aload(rS + tid) * invPR;
    __syncthreads();                                    // S5: r visible; mem ordered for next P1
    // register-resident r-part completes co_{t+1}
    if (gthr) {
#pragma unroll
      for (int q = 0; q < 8; ++q) {
        const float4 xv = *(const float4*)(xin + 128 + 32 * hh + 4 * q);
        nacc = fmaf(xv.x, wreg[4 * q + 0], nacc);
        nacc = fmaf(xv.y, wreg[4 * q + 1], nacc);
        nacc = fmaf(xv.z, wreg[4 * q + 2], nacc);
        nacc = fmaf(xv.w, wreg[4 * q + 3], nacc);
      }
    }
    acc = nacc;
  }
}

extern "C" void kernel_launch(void* const* d_in, const int* in_sizes, int n_in,
                              void* d_out, int out_size, void* d_ws, size_t ws_size,
                              hipStream_t stream) {
  const float* inp = (const float*)d_in[0];
  const float* Wc  = (const float*)d_in[1];
  const float* bcv = (const float*)d_in[2];
  float* dout = (float*)d_out;
  float* comm = (float*)d_ws;

  hipMemsetAsync(comm, 0, (size_t)COMM_FLOATS * sizeof(float), stream);

  void* args[] = { (void*)&inp, (void*)&Wc, (void*)&bcv, (void*)&dout, (void*)&comm };
  hipLaunchCooperativeKernel((void*)ntm_kernel, dim3(NBLK), dim3(NTHR),
                             args, 0, stream);
}

// Round 6
// 776.202 us; speedup vs baseline: 1.1467x; 1.1467x over previous
//
#include <hip/hip_runtime.h>

#define T_STEPS 32
#define BATCH   16
#define NBPB    8                    // blocks per batch
#define NBLK    (BATCH * NBPB)       // 128
#define NTHR    1024
#define LSL     512                  // l-slots per block
#define MSTR    65                   // bank (l+w)%32 -> 2-way (free); scalar access only
#define NIN     192
#define CO      332

// comm workspace (floats), zeroed by hipMemsetAsync each launch
#define OFF_CTR   0                                        // [16][32] uints (barrier ctrs)
#define OFF_SSUM  512                                      // [b][t][4]  S_R,S_W,P_R,P_W
#define OFF_RSUM  (OFF_SSUM + BATCH * T_STEPS * 4)         // [b][t][64] unnormalized read partials
#define OFF_HE    (OFF_RSUM + BATCH * T_STEPS * 64)        // [b][t][g][4] er halos
#define OFF_HP    (OFF_HE + BATCH * T_STEPS * NBPB * 4)    // [b][t=0..32][g][4] normalized wp halos
#define COMM_FLOATS (OFF_HP + BATCH * (T_STEPS + 1) * NBPB * 4)

__device__ __forceinline__ float waveSum(float v) {
#pragma unroll
  for (int off = 32; off > 0; off >>= 1) v += __shfl_xor(v, off, 64);
  return v;
}
__device__ __forceinline__ float sigmoidf(float x) { return 1.f / (1.f + __expf(-x)); }
__device__ __forceinline__ float softplusf(float x) { return x > 15.f ? x : log1pf(__expf(x)); }
__device__ __forceinline__ float aload(const float* p) {
  return __hip_atomic_load(p, __ATOMIC_RELAXED, __HIP_MEMORY_SCOPE_AGENT);
}
__device__ __forceinline__ void astore(float* p, float v) {
  __hip_atomic_store(p, v, __ATOMIC_RELAXED, __HIP_MEMORY_SCOPE_AGENT);
}
// tid0-only spin (L2-friendly); caller supplies surrounding __syncthreads
__device__ __forceinline__ void spin_until(const unsigned* c, unsigned expected) {
  while (__hip_atomic_load(c, __ATOMIC_RELAXED, __HIP_MEMORY_SCOPE_AGENT) < expected)
    __builtin_amdgcn_s_sleep(1);
}

// launch_bounds(1024, 4): 16 waves/block = 4 waves/EU -> VGPR budget 128.
// (With the default the compiler targets 64 VGPRs and spills wreg[] to scratch:
//  round-1 showed WRITE_SIZE 4->22 MB from exactly this.)
__global__ void __launch_bounds__(NTHR, 4) ntm_kernel(
    const float* __restrict__ inp, const float* __restrict__ Wc,
    const float* __restrict__ bcv, float* __restrict__ dout,
    float* __restrict__ comm)
{
  // XCD co-location: blockIdx = g*16 + b -> all 8 blocks of a batch on one XCD.
  const int b    = blockIdx.x & 15;
  const int g    = blockIdx.x >> 4;
  const int tid  = threadIdx.x;
  const int wv   = tid >> 6;
  const int lane = tid & 63;

  __shared__ float mem[LSL * MSTR];               // 133 KB, block-private
  __shared__ float wpR[LSL], wpW[LSL];            // normalized prev weights
  __shared__ float wbR[LSL], wbW[LSL];            // sharpened, unnormalized
  __shared__ float erR[LSL], erW[LSL];            // softmax numerators
  __shared__ __align__(16) float xin[NIN];
  __shared__ float kr[64], kw[64], elds[64], alds[64];
  __shared__ float psc[12], outb[64], scrA[16], scrB[16];

  unsigned* ctr = (unsigned*)comm + b * 32;

  // GEMM role: 2 threads per output column
  const int col  = tid >> 1;
  const int hh   = tid & 1;
  const bool gthr = (col < CO);

  // r-part Wc rows 128..191 held in registers (loop-invariant): 32 VGPRs/thread
  float wreg[32];
  if (gthr) {
#pragma unroll
    for (int i = 0; i < 32; ++i)
      wreg[i] = Wc[(size_t)(128 + 32 * hh + i) * CO + col];
  }

  // ---------------- prologue (no global barrier needed: halo stores become
  // visible at barrier A of t=0, before any neighbor reads them) ----------------
  for (int i = tid; i < LSL * MSTR; i += NTHR) mem[i] = 0.f;
  if (tid < LSL) { wpR[tid] = 0.f; wpW[tid] = 0.f; }
  if (g == 0 && tid == 0) { wpR[0] = 1.f; wpW[0] = 1.f; }   // w0 one-hot at l=0
  if (tid < 64)            xin[tid] = inp[(size_t)b * 64 + tid];   // x_0
  else if (tid < NIN)      xin[tid] = 0.f;                          // out_{-1}=0, r_{-1}=0
  {
    float* hp0 = comm + OFF_HP + ((size_t)(b * (T_STEPS + 1)) * NBPB + g) * 4;
    if (tid == 0) { float v = (g == 0) ? 1.f : 0.f; astore(hp0 + 0, v); astore(hp0 + 2, v); }
    if (tid == 1) { astore(hp0 + 1, 0.f); astore(hp0 + 3, 0.f); }
  }
  __syncthreads();

  // initial GEMM: co_0 (r-part multiplies zeros; kept for uniformity)
  float acc = 0.f;
  if (gthr) {
    acc = hh ? 0.f : bcv[col];
    const float* wcx = Wc + col + (size_t)(64 * hh) * CO;
#pragma unroll 4
    for (int q = 0; q < 16; ++q) {
      const float4 xv = *(const float4*)(xin + 64 * hh + 4 * q);
      acc = fmaf(xv.x, wcx[(size_t)(4 * q + 0) * CO], acc);
      acc = fmaf(xv.y, wcx[(size_t)(4 * q + 1) * CO], acc);
      acc = fmaf(xv.z, wcx[(size_t)(4 * q + 2) * CO], acc);
      acc = fmaf(xv.w, wcx[(size_t)(4 * q + 3) * CO], acc);
    }
#pragma unroll
    for (int q = 0; q < 8; ++q) {
      const float4 xv = *(const float4*)(xin + 128 + 32 * hh + 4 * q);
      acc = fmaf(xv.x, wreg[4 * q + 0], acc);
      acc = fmaf(xv.y, wreg[4 * q + 1], acc);
      acc = fmaf(xv.z, wreg[4 * q + 2], acc);
      acc = fmaf(xv.w, wreg[4 * q + 3], acc);
    }
  }

  const int gm = (g + NBPB - 1) & 7, gp = (g + 1) & 7;
  unsigned expct = 0;

  for (int t = 0; t < T_STEPS; ++t) {
    float* sS        = comm + OFF_SSUM + (size_t)(b * T_STEPS + t) * 4;
    float* rS        = comm + OFF_RSUM + (size_t)(b * T_STEPS + t) * 64;
    float* hE        = comm + OFF_HE + ((size_t)(b * T_STEPS + t) * NBPB + g) * 4;
    float* hPn       = comm + OFF_HP + ((size_t)(b * (T_STEPS + 1) + t + 1) * NBPB + g) * 4;
    const float* hEm = comm + OFF_HE + ((size_t)(b * T_STEPS + t) * NBPB + gm) * 4;
    const float* hPm = comm + OFF_HP + ((size_t)(b * (T_STEPS + 1) + t) * NBPB + gm) * 4;
    const float* hEp = comm + OFF_HE + ((size_t)(b * T_STEPS + t) * NBPB + gp) * 4;
    const float* hPp = comm + OFF_HP + ((size_t)(b * (T_STEPS + 1) + t) * NBPB + gp) * 4;

    // ------- finalize co_t from register accumulators -------
    if (gthr) {
      float v = acc + __shfl_xor(acc, 1, 64);
      if (hh == 0) {
        if (col < 64) {
          outb[col] = v;
          if (g == 0) dout[((size_t)t * BATCH + b) * 64 + col] = v;
        }
        else if (col < 128) kr[col - 64] = v;
        else if (col < 134) psc[col - 128] = v;        // beta_r,g_r,ga_r,s_r0..2
        else if (col < 198) kw[col - 134] = v;
        else if (col < 204) psc[6 + (col - 198)] = v;  // beta_w,g_w,ga_w,s_w0..2
        else if (col < 268) elds[col - 204] = sigmoidf(v);
        else                alds[col - 268] = v;
      }
    }
    __syncthreads();                                    // S1: co_t distributed

    // ------- P1: content addressing (2 threads per l, scalar reads, MSTR=65) -------
    {
      // per-wave redundant key norms (saves 2 block syncs vs dedicated waves)
      float vr = kr[lane]; float nr = waveSum(vr * vr);
      float vw = kw[lane]; float nw = waveSum(vw * vw);
      const float invnkR = rsqrtf(nr + 1e-14f);
      const float invnkW = rsqrtf(nw + 1e-14f);
      const float betaR = softplusf(psc[0]), betaW = softplusf(psc[6]);

      const int l = tid >> 1, h = tid & 1;
      const int base = l * MSTR + 32 * h;
      const float* krh = kr + 32 * h;
      const float* kwh = kw + 32 * h;
      float ss = 0.f, dr = 0.f, dw = 0.f;
#pragma unroll 8
      for (int i = 0; i < 32; ++i) {
        float v = mem[base + i];
        ss = fmaf(v, v, ss); dr = fmaf(v, krh[i], dr); dw = fmaf(v, kwh[i], dw);
      }
      ss += __shfl_xor(ss, 1, 64);
      dr += __shfl_xor(dr, 1, 64);
      dw += __shfl_xor(dw, 1, 64);
      float rinv = rsqrtf(ss + 1e-14f);
      float eRv = __expf(betaR * (dr * rinv * invnkR - 1.f));   // stable: K<=1
      float eWv = __expf(betaW * (dw * rinv * invnkW - 1.f));
      if (h == 0) {
        erR[l] = eRv; erW[l] = eWv;
        if (l == 0)       { astore(hE + 0, eRv); astore(hE + 2, eWv); }
        if (l == LSL - 1) { astore(hE + 1, eRv); astore(hE + 3, eWv); }
      }
      float sRl = waveSum(h ? 0.f : eRv);
      float sWl = waveSum(h ? 0.f : eWv);
      if (!lane) { scrA[wv] = sRl; scrB[wv] = sWl; }
    }
    __syncthreads();                                    // S2: drains halos + scr
    if (tid == 0) {
      float a = 0.f, bb = 0.f;
#pragma unroll
      for (int j = 0; j < 16; ++j) { a += scrA[j]; bb += scrB[j]; }
      atomicAdd(sS + 0, a); atomicAdd(sS + 1, bb);
      __hip_atomic_fetch_add(ctr, 1u, __ATOMIC_RELEASE, __HIP_MEMORY_SCOPE_AGENT);
    }
    expct += NBPB;
    // barrier-A shadow: stage next-step xin[0..127] (x_{t+1}, out_t)
    {
      const int tt = (t + 1 < T_STEPS) ? (t + 1) : (T_STEPS - 1);
      if (tid < 64)       xin[tid] = inp[((size_t)tt * BATCH + b) * 64 + tid];
      else if (tid < 128) xin[tid] = outb[tid - 64];
    }
    if (tid == 0) spin_until(ctr, expct);
    __syncthreads();                                    // S3: barrier A resolved

    // ------- P2: sharpen (h=0 read head, h=1 write head; redundant coefs) -------
    {
      const int l = tid >> 1, h = tid & 1;
      const float S = aload(sS + h);                    // L2 broadcast
      const float gg_ = sigmoidf(psc[6 * h + 1]);
      const float aH = gg_ / S, bH = 1.f - gg_;
      const float gaH = softplusf(psc[6 * h + 2]) + 1.f;
      float x0 = psc[6 * h + 3], x1 = psc[6 * h + 4], x2 = psc[6 * h + 5];
      float mx = fmaxf(x0, fmaxf(x1, x2));
      float e0 = __expf(x0 - mx), e1 = __expf(x1 - mx), e2 = __expf(x2 - mx);
      float es = 1.f / (e0 + e1 + e2);
      const float c0 = e0 * es, c1 = e1 * es, c2 = e2 * es;

      const float* er = h ? erW : erR;
      const float* wp = h ? wpW : wpR;
      float em, pm, ep, pp;
      if (l == 0) { em = aload(hEm + 2 * h + 1); pm = aload(hPm + 2 * h + 1); }
      else        { em = er[l - 1];              pm = wp[l - 1]; }
      if (l == LSL - 1) { ep = aload(hEp + 2 * h); pp = aload(hPp + 2 * h); }
      else              { ep = er[l + 1];          pp = wp[l + 1]; }

      float wgm = aH * em + bH * pm;
      float wg0 = aH * er[l] + bH * wp[l];
      float wgp = aH * ep + bH * pp;
      float wb = __powf(c0 * wgm + c1 * wg0 + c2 * wgp, gaH);
      (h ? wbW : wbR)[l] = wb;
      float sRl = waveSum(h ? 0.f : wb);
      float sWl = waveSum(h ? wb : 0.f);
      if (!lane) { scrA[wv] = sRl; scrB[wv] = sWl; }
    }
    __syncthreads();                                    // S4: wb visible for rpart

    // ------- unnormalized read partials over OLD memory (scalar, MSTR=65) -------
    {
      float wbv[8];
#pragma unroll
      for (int k = 0; k < 8; ++k) wbv[k] = wbR[lane + 64 * k];
#pragma unroll
      for (int r2 = 0; r2 < 4; ++r2) {
        const int w = wv * 4 + r2;
        float racc = 0.f;
#pragma unroll
        for (int k = 0; k < 8; ++k)
          racc = fmaf(mem[(lane + 64 * k) * MSTR + w], wbv[k], racc);
        racc = waveSum(racc);
        if (!lane) atomicAdd(rS + w, racc);             // direct per-wave publish
      }
    }
    __syncthreads();                                    // S5: drains rS atomics + scr
    if (tid == 0) {
      float a = 0.f, bb = 0.f;
#pragma unroll
      for (int j = 0; j < 16; ++j) { a += scrA[j]; bb += scrB[j]; }
      atomicAdd(sS + 2, a); atomicAdd(sS + 3, bb);
      __hip_atomic_fetch_add(ctr, 1u, __ATOMIC_RELEASE, __HIP_MEMORY_SCOPE_AGENT);
    }
    expct += NBPB;
    // barrier-B shadow: xo-part of co_{t+1} (rows 0..127 of Wc, from staged xin)
    float nacc = 0.f;
    if (gthr) {
      nacc = hh ? 0.f : bcv[col];
      const float* wcx = Wc + col + (size_t)(64 * hh) * CO;
#pragma unroll 4
      for (int q = 0; q < 16; ++q) {
        const float4 xv = *(const float4*)(xin + 64 * hh + 4 * q);
        nacc = fmaf(xv.x, wcx[(size_t)(4 * q + 0) * CO], nacc);
        nacc = fmaf(xv.y, wcx[(size_t)(4 * q + 1) * CO], nacc);
        nacc = fmaf(xv.z, wcx[(size_t)(4 * q + 2) * CO], nacc);
        nacc = fmaf(xv.w, wcx[(size_t)(4 * q + 3) * CO], nacc);
      }
    }
    if (tid == 0) spin_until(ctr, expct);
    __syncthreads();                                    // S6: barrier B resolved

    // ------- P3: normalize + memory update (per-thread redundant 1/P) -------
    {
      const float raw = (tid < 64) ? aload(rS + tid) : 0.f;
      const float invPR = 1.f / aload(sS + 2);
      const float invPW = 1.f / aload(sS + 3);
      if (tid < LSL) {
        const float nR = wbR[tid] * invPR;
        const float nW = wbW[tid] * invPW;
        wpR[tid] = nR; wpW[tid] = nW;                   // w_prev for t+1
        if (tid == 0)       { astore(hPn + 0, nR); astore(hPn + 2, nW); }
        if (tid == LSL - 1) { astore(hPn + 1, nR); astore(hPn + 3, nW); }
      }
      if (tid < 64) xin[128 + tid] = raw * invPR;       // r_t for co_{t+1}
      float wwv[8];
#pragma unroll
      for (int k = 0; k < 8; ++k) wwv[k] = wbW[lane + 64 * k] * invPW;
#pragma unroll
      for (int r2 = 0; r2 < 4; ++r2) {
        const int w = wv * 4 + r2;
        const float e_w = elds[w], a_w = alds[w];
#pragma unroll
        for (int k = 0; k < 8; ++k) {
          const int idx = (lane + 64 * k) * MSTR + w;
          float v = mem[idx];
          float nv = fmaf(v, -(wwv[k] * e_w), v);       // v*(1 - ww*e)
          mem[idx] = fmaf(wwv[k], a_w, nv);             // + ww*a
        }
      }
    }
    __syncthreads();                                    // S7: r staged; mem ordered

    // register-resident r-part completes co_{t+1}
    if (gthr) {
#pragma unroll
      for (int q = 0; q < 8; ++q) {
        const float4 xv = *(const float4*)(xin + 128 + 32 * hh + 4 * q);
        nacc = fmaf(xv.x, wreg[4 * q + 0], nacc);
        nacc = fmaf(xv.y, wreg[4 * q + 1], nacc);
        nacc = fmaf(xv.z, wreg[4 * q + 2], nacc);
        nacc = fmaf(xv.w, wreg[4 * q + 3], nacc);
      }
    }
    acc = nacc;
  }
}

extern "C" void kernel_launch(void* const* d_in, const int* in_sizes, int n_in,
                              void* d_out, int out_size, void* d_ws, size_t ws_size,
                              hipStream_t stream) {
  const float* inp = (const float*)d_in[0];
  const float* Wc  = (const float*)d_in[1];
  const float* bcv = (const float*)d_in[2];
  float* dout = (float*)d_out;
  float* comm = (float*)d_ws;

  hipMemsetAsync(comm, 0, (size_t)COMM_FLOATS * sizeof(float), stream);

  void* args[] = { (void*)&inp, (void*)&Wc, (void*)&bcv, (void*)&dout, (void*)&comm };
  hipLaunchCooperativeKernel((void*)ntm_kernel, dim3(NBLK), dim3(NTHR),
                             args, 0, stream);
}